// Round 2
// baseline (164.334 us; speedup 1.0000x reference)
//
#include <hip/hip_runtime.h>
#include <stdint.h>

#define ALPHA 0.2f
#define NEG_BIG -9000000000000000.0f
#define L2E 1.4426950408889634f

typedef __attribute__((ext_vector_type(8))) short bf16x8;
typedef __attribute__((ext_vector_type(8))) unsigned short u16x8;
typedef __attribute__((ext_vector_type(4))) float f32x4;

__device__ __forceinline__ unsigned short f2bf(float f) {
    unsigned int u = __float_as_uint(f);
    u += 0x7fffu + ((u >> 16) & 1u);   // RNE
    return (unsigned short)(u >> 16);
}

__device__ __forceinline__ void gload_lds16(const void* g, void* l) {
    __builtin_amdgcn_global_load_lds(
        (const __attribute__((address_space(1))) unsigned int*)g,
        (__attribute__((address_space(3))) unsigned int*)l, 16, 0, 0);
}

// lgkm-only barrier: drains LDS ops but leaves global loads in flight
// (avoids the vmcnt(0) drain __syncthreads() would emit).
__device__ __forceinline__ void bar_lds() {
    asm volatile("s_waitcnt lgkmcnt(0)" ::: "memory");
    __builtin_amdgcn_s_barrier();
}

// ---------------------------------------------------------------------------
// Blocks 0..255: Wtbf[o*256+t] = bf16(W[t*256+o]).
// Block 256:     wa[k] = W[k,:]·a_l ; wa[256+k] = W[k,:]·a_r  (fp32).
// ---------------------------------------------------------------------------
__global__ void wt_wa_kernel(const float* __restrict__ W,
                             const float* __restrict__ a,
                             unsigned short* __restrict__ Wtbf,
                             float* __restrict__ wa) {
    const int t = threadIdx.x;
    if (blockIdx.x < 256) {
        const int o = blockIdx.x;
        Wtbf[o * 256 + t] = f2bf(W[t * 256 + o]);
    } else {
        float sl = 0.f, sr = 0.f;
        const float* wr = W + t * 256;
        for (int o = 0; o < 256; ++o) {
            const float wv = wr[o];
            sl += wv * a[o];
            sr += wv * a[256 + o];
        }
        wa[t] = sl;
        wa[256 + t] = sr;
    }
}

// ---------------------------------------------------------------------------
// One wave per row r: el2[r] = (x[r,:]·wa_l)*log2(e), er2 likewise,
// and xbf[r,:] = bf16(x[r,:]).  (log2-domain: exp(x) == exp2(x*L2E);
// leaky-relu commutes with positive scaling, so scale once here.)
// ---------------------------------------------------------------------------
__global__ __launch_bounds__(256) void eler2x_kernel(
    const float* __restrict__ x, const float* __restrict__ wa,
    float* __restrict__ el, float* __restrict__ er,
    unsigned short* __restrict__ xbf)
{
    const int w = threadIdx.x >> 6, l = threadIdx.x & 63;
    const int r = blockIdx.x * 4 + w;       // 0..16383
    const float4 xv = *(const float4*)(x + (size_t)r * 256 + l * 4);
    const float4 al = *(const float4*)(wa + l * 4);
    const float4 ar = *(const float4*)(wa + 256 + l * 4);

    ushort4 xb;
    xb.x = f2bf(xv.x); xb.y = f2bf(xv.y); xb.z = f2bf(xv.z); xb.w = f2bf(xv.w);
    *(ushort4*)(xbf + (size_t)r * 256 + l * 4) = xb;

    float sl = xv.x * al.x + xv.y * al.y + xv.z * al.z + xv.w * al.w;
    float sr = xv.x * ar.x + xv.y * ar.y + xv.z * ar.z + xv.w * ar.w;
#pragma unroll
    for (int off = 32; off >= 1; off >>= 1) {
        sl += __shfl_xor(sl, off);
        sr += __shfl_xor(sr, off);
    }
    if (l == 0) { el[r] = sl * L2E; er[r] = sr * L2E; }
}

// ---------------------------------------------------------------------------
// h_T (256 x 16384) = Wtbf (256x256) @ xbf^T.  Flat batched GEMM.
// 64(m) x 128(n) tiles, K-step 64, grid (128,4) = 512 blocks (2/CU).
// ---------------------------------------------------------------------------
__global__ __launch_bounds__(256) void gemm_h(
    const unsigned short* __restrict__ A,    // Wtbf 256x256
    const unsigned short* __restrict__ Bt,   // xbf 16384x256
    unsigned short* __restrict__ C)          // h_T 256x16384
{
    __shared__ __align__(16) unsigned short As[64 * 64];    //  8 KB
    __shared__ __align__(16) unsigned short Bs[128 * 64];   // 16 KB

    const int tid = threadIdx.x;
    const int w = tid >> 6, l = tid & 63;
    const int q = l >> 4, ml = l & 15;
    const int wm = (w >> 1) * 32;
    const int wn = (w & 1) * 64;
    const int m0 = blockIdx.y * 64;
    const int n0 = blockIdx.x * 128;

    f32x4 acc[2][4];
    for (int i = 0; i < 2; ++i)
        for (int j = 0; j < 4; ++j) {
            f32x4 z = {0.f, 0.f, 0.f, 0.f};
            acc[i][j] = z;
        }

    for (int k0 = 0; k0 < 256; k0 += 64) {
        for (int c = 0; c < 2; ++c) {
            const int cb = c * 256 + (w << 6);
            const int p = cb + l;
            const int r = p >> 3;
            const int cc = (p & 7) ^ (r & 7);
            gload_lds16(A + (size_t)(m0 + r) * 256 + k0 + cc * 8, As + cb * 8);
        }
        for (int c = 0; c < 4; ++c) {
            const int cb = c * 256 + (w << 6);
            const int p = cb + l;
            const int r = p >> 3;
            const int cc = (p & 7) ^ (r & 7);
            gload_lds16(Bt + (size_t)(n0 + r) * 256 + k0 + cc * 8, Bs + cb * 8);
        }
        __syncthreads();

        bf16x8 aF[2][2], bF[2][4];
#pragma unroll
        for (int ks = 0; ks < 2; ++ks) {
#pragma unroll
            for (int mt = 0; mt < 2; ++mt) {
                const int mm = wm + mt * 16 + ml;
                aF[ks][mt] = *(const bf16x8*)(As + (mm * 8 + ((ks * 4 + q) ^ (mm & 7))) * 8);
            }
#pragma unroll
            for (int nt = 0; nt < 4; ++nt) {
                const int nn = wn + nt * 16 + ml;
                bF[ks][nt] = *(const bf16x8*)(Bs + (nn * 8 + ((ks * 4 + q) ^ (nn & 7))) * 8);
            }
        }
#pragma unroll
        for (int ks = 0; ks < 2; ++ks)
            for (int mt = 0; mt < 2; ++mt)
                for (int nt = 0; nt < 4; ++nt)
                    acc[mt][nt] = __builtin_amdgcn_mfma_f32_16x16x32_bf16(
                        aF[ks][mt], bF[ks][nt], acc[mt][nt], 0, 0, 0);
        __syncthreads();
    }

    for (int mt = 0; mt < 2; ++mt)
        for (int nt = 0; nt < 4; ++nt) {
            const int gn = n0 + wn + nt * 16 + ml;
            for (int r = 0; r < 4; ++r) {
                const int gm = m0 + wm + mt * 16 + q * 4 + r;
                C[(size_t)gm * 16384 + gn] = f2bf(acc[mt][nt][r]);
            }
        }
}

// ---------------------------------------------------------------------------
// Mask pre-pass, log2 domain. One wave per row.
// c2[row] = m2 + log2(sum 2^(e2-m2));  adjacency packed to pk16.
// ---------------------------------------------------------------------------
__global__ __launch_bounds__(256) void mask_kernel(
    const int* __restrict__ adj,
    const float* __restrict__ el,     // log2-scaled
    const float* __restrict__ er,     // log2-scaled
    float* __restrict__ c,            // log2-domain logsumexp
    unsigned short* __restrict__ pk16)
{
    __shared__ unsigned char nibs[4][256];

    const int w = threadIdx.x >> 6, l = threadIdx.x & 63;
    const int row = blockIdx.x * 4 + w;       // 0..16383
    const int b = row >> 10;
    const int* arow = adj + (size_t)row * 1024;
    const float* erb = er + (b << 10);
    const float eli = el[row];

    float ev[16];
    float m = -3.0e38f;
#pragma unroll
    for (int it = 0; it < 4; ++it) {
        const int j = it * 256 + l * 4;
        const int4 av = *(const int4*)(arow + j);
        const float4 erv = *(const float4*)(erb + j);
        float e0 = eli + erv.x; e0 = e0 > 0.f ? e0 : ALPHA * e0; e0 = av.x > 0 ? e0 : NEG_BIG;
        float e1 = eli + erv.y; e1 = e1 > 0.f ? e1 : ALPHA * e1; e1 = av.y > 0 ? e1 : NEG_BIG;
        float e2 = eli + erv.z; e2 = e2 > 0.f ? e2 : ALPHA * e2; e2 = av.z > 0 ? e2 : NEG_BIG;
        float e3 = eli + erv.w; e3 = e3 > 0.f ? e3 : ALPHA * e3; e3 = av.w > 0 ? e3 : NEG_BIG;
        ev[it * 4 + 0] = e0; ev[it * 4 + 1] = e1;
        ev[it * 4 + 2] = e2; ev[it * 4 + 3] = e3;
        m = fmaxf(m, fmaxf(fmaxf(e0, e1), fmaxf(e2, e3)));
        nibs[w][it * 64 + l] =
            (unsigned char)((av.x > 0) | ((av.y > 0) << 1) |
                            ((av.z > 0) << 2) | ((av.w > 0) << 3));
    }
#pragma unroll
    for (int off = 32; off >= 1; off >>= 1) m = fmaxf(m, __shfl_xor(m, off));
    float s = 0.f;
#pragma unroll
    for (int u = 0; u < 16; ++u) s += exp2f(ev[u] - m);
#pragma unroll
    for (int off = 32; off >= 1; off >>= 1) s += __shfl_xor(s, off);
    if (l == 0) c[row] = m + log2f(s);

    const unsigned nr = *(const unsigned int*)(&nibs[w][l * 4]);
    const unsigned short mask16 =
        (unsigned short)((nr & 0xFu) | ((nr >> 4) & 0xF0u) |
                         ((nr >> 8) & 0xF00u) | ((nr >> 12) & 0xF000u));
    pk16[(size_t)row * 64 + l] = mask16;
}

// ---------------------------------------------------------------------------
// PV: out[b, i0..i0+63, :] = P @ h[b].
// Grid 256 blocks (1/CU), 512 threads (8 waves: 2m x 4n, wave = 32m x 64o).
// - No H staging: B-fragments of mfma_16x16x32 are 16 contiguous bytes of an
//   hT row -> load straight from global (L2), software-prefetched 1 j-step
//   ahead; the per-row ks=0/ks=1 pair covers a full aligned 128B line.
// - P tile (64 x 64) double-buffered in LDS; one lgkm-only barrier per
//   j-step (raw s_barrier, no vmcnt drain -> prefetch stays in flight).
// - XCD-aware decode: batch b = (lin&7)*2 + ((lin>>3)&1) pins each h[b]
//   (512 KB, re-read 16x) into a single XCD's 4 MB L2.
// ---------------------------------------------------------------------------
__global__ __launch_bounds__(512, 2) void pv_kernel(
    const unsigned short* __restrict__ pk16,
    const float* __restrict__ el2,
    const float* __restrict__ er2,
    const float* __restrict__ c2,
    const unsigned short* __restrict__ hT,   // 256 x 16384 (row stride 16384)
    float* __restrict__ out)
{
    __shared__ float er_s[1024];
    __shared__ __align__(16) unsigned short pk_s[64 * 72];   // stride 72: 16B-aligned rows
    __shared__ __align__(16) unsigned short Ps[2 * 64 * 72]; // dbuf, pad->~2-way max

    const int tid = threadIdx.x;
    const int w = tid >> 6, l = tid & 63;
    const int q = l >> 4, ml = l & 15;
    const int wm = (w >> 2) * 32;       // 0 | 32
    const int wn = (w & 3) * 64;        // 0..192

    const int lin = blockIdx.x;
    const int b = ((lin & 7) << 1) | ((lin >> 3) & 1);  // 2 batches per XCD
    const int i0 = (lin >> 4) * 64;

    // ---- init LDS (er row, packed mask rows) ----
    *(float2*)(er_s + tid * 2) = *(const float2*)(er2 + (b << 10) + tid * 2);
    {
        const int pr = tid >> 3, pc = (tid & 7) * 8;
        *(u16x8*)(pk_s + pr * 72 + pc) =
            *(const u16x8*)(pk16 + ((size_t)((b << 10) + i0 + pr)) * 64 + pc);
    }

    // P-build mapping: thread -> row ib, cols js..js+7 of the 64-wide j tile
    const int ib = tid >> 3;
    const int js = (tid & 7) * 8;
    const int rg = (b << 10) + i0 + ib;
    const float el2i = el2[rg];
    const float c2i = c2[rg];

    f32x4 acc[2][4];
#pragma unroll
    for (int i = 0; i < 2; ++i)
#pragma unroll
        for (int j = 0; j < 4; ++j) {
            f32x4 z = {0.f, 0.f, 0.f, 0.f};
            acc[i][j] = z;
        }

    const unsigned short* hb = hT + (size_t)b * 1024;
    const unsigned short* bp[4];
#pragma unroll
    for (int nt = 0; nt < 4; ++nt)
        bp[nt] = hb + (size_t)(wn + nt * 16 + ml) * 16384 + q * 8;

    bf16x8 B0[2][4], B1[2][4];

#define LOADB(B, t) do {                                                      \
    _Pragma("unroll")                                                         \
    for (int nt_ = 0; nt_ < 4; ++nt_) {                                       \
        B[0][nt_] = *(const bf16x8*)(bp[nt_] + (t) * 64);                     \
        B[1][nt_] = *(const bf16x8*)(bp[nt_] + (t) * 64 + 32);                \
    } } while (0)

#define BUILD(BI, t) do {                                                     \
    const int j0_ = (t) * 64;                                                 \
    float ev8[8];                                                             \
    *(f32x4*)(ev8)     = *(const f32x4*)(er_s + j0_ + js);                    \
    *(f32x4*)(ev8 + 4) = *(const f32x4*)(er_s + j0_ + js + 4);                \
    const unsigned hw_ = pk_s[ib * 72 + ((j0_ + js) >> 4)];                   \
    const unsigned mv_ = (hw_ >> (js & 8)) & 0xFFu;                           \
    u16x8 pv_;                                                                \
    _Pragma("unroll")                                                         \
    for (int u_ = 0; u_ < 8; ++u_) {                                          \
        float e_ = el2i + ev8[u_];                                            \
        e_ = fmaxf(e_, ALPHA * e_);   /* leaky-relu, valid: scale > 0 */      \
        float p_ = exp2f(e_ - c2i);                                           \
        p_ = ((mv_ >> u_) & 1u) ? p_ : 0.f;                                   \
        pv_[u_] = f2bf(p_);                                                   \
    }                                                                         \
    *(u16x8*)(Ps + (BI) * (64 * 72) + ib * 72 + js) = pv_;                    \
    } while (0)

#define COMPUTE(BI, B) do {                                                   \
    bf16x8 aF[2][2];                                                          \
    _Pragma("unroll")                                                         \
    for (int ks_ = 0; ks_ < 2; ++ks_)                                         \
        _Pragma("unroll")                                                     \
        for (int mt_ = 0; mt_ < 2; ++mt_)                                     \
            aF[ks_][mt_] = *(const bf16x8*)(Ps + (BI) * (64 * 72) +           \
                (wm + mt_ * 16 + ml) * 72 + ks_ * 32 + q * 8);                \
    _Pragma("unroll")                                                         \
    for (int ks_ = 0; ks_ < 2; ++ks_)                                         \
        _Pragma("unroll")                                                     \
        for (int mt_ = 0; mt_ < 2; ++mt_)                                     \
            _Pragma("unroll")                                                 \
            for (int nt_ = 0; nt_ < 4; ++nt_)                                 \
                acc[mt_][nt_] = __builtin_amdgcn_mfma_f32_16x16x32_bf16(      \
                    aF[ks_][mt_], B[ks_][nt_], acc[mt_][nt_], 0, 0, 0);       \
    } while (0)

    __syncthreads();          // init LDS visible (full drain fine here, once)
    LOADB(B0, 0);

    for (int t = 0; t < 16; t += 2) {
        BUILD(0, t);                      // write Ps[0]
        LOADB(B1, t + 1);                 // prefetch next B, stays in flight
        bar_lds();
        COMPUTE(0, B0);                   // read Ps[0] + MFMA
        BUILD(1, t + 1);                  // write Ps[1] (safe: after barrier)
        if (t + 2 < 16) LOADB(B0, t + 2);
        bar_lds();
        COMPUTE(1, B1);
    }

#undef LOADB
#undef BUILD
#undef COMPUTE

    // D layout: col=lane&15, row=(lane>>4)*4+reg
    float* ob = out + (size_t)b * 262144;
#pragma unroll
    for (int mt = 0; mt < 2; ++mt)
#pragma unroll
        for (int nt = 0; nt < 4; ++nt) {
            const int gn = wn + nt * 16 + ml;
#pragma unroll
            for (int r = 0; r < 4; ++r) {
                const int gm = i0 + wm + mt * 16 + q * 4 + r;
                ob[(size_t)gm * 256 + gn] = acc[mt][nt][r];
            }
        }
}

// ---------------------------------------------------------------------------
// Workspace (~19.2 MB):
//   Wtbf (bf16) @ 0        : 131072
//   wa   (f32)  @ 131072   : 2048
//   xbf  (bf16) @ 133120   : 8388608   (16384 x 256)
//   h_T  (bf16) @ 8521728  : 8388608   (256 x 16384)
//   el2  (f32)  @ 16910336 : 65536    (log2-scaled)
//   er2  (f32)  @ 16975872 : 65536    (log2-scaled)
//   c2   (f32)  @ 17041408 : 65536    (log2-domain logsumexp)
//   pk16 (u16)  @ 17106944 : 2097152
// ---------------------------------------------------------------------------
extern "C" void kernel_launch(void* const* d_in, const int* in_sizes, int n_in,
                              void* d_out, int out_size, void* d_ws, size_t ws_size,
                              hipStream_t stream) {
    const float* x   = (const float*)d_in[0];   // (16,1024,256) fp32
    const int*   adj = (const int*)d_in[1];     // (16,1024,1024) int32
    const float* W   = (const float*)d_in[2];   // (256,256) fp32
    const float* a   = (const float*)d_in[3];   // (512,1) fp32
    float* out = (float*)d_out;                 // (16,1024,256) fp32

    char* ws = (char*)d_ws;
    unsigned short* Wtbf  = (unsigned short*)(ws);
    float* wa             = (float*)(ws + 131072);
    unsigned short* xbf   = (unsigned short*)(ws + 133120);
    unsigned short* h_T   = (unsigned short*)(ws + 8521728);
    float* el             = (float*)(ws + 16910336);
    float* er             = (float*)(ws + 16975872);
    float* c              = (float*)(ws + 17041408);
    unsigned short* pk16  = (unsigned short*)(ws + 17106944);

    wt_wa_kernel<<<dim3(257), dim3(256), 0, stream>>>(W, a, Wtbf, wa);

    eler2x_kernel<<<dim3(4096), dim3(256), 0, stream>>>(x, wa, el, er, xbf);

    // h_T (256 x 16384) = Wtbf @ xbf^T
    gemm_h<<<dim3(128, 4), dim3(256), 0, stream>>>(Wtbf, xbf, h_T);

    mask_kernel<<<dim3(4096), dim3(256), 0, stream>>>(adj, el, er, c, pk16);

    pv_kernel<<<dim3(256), dim3(512), 0, stream>>>(pk16, el, er, c, h_T, out);
}

// Round 3
// 157.858 us; speedup vs baseline: 1.0410x; 1.0410x over previous
//
#include <hip/hip_runtime.h>
#include <stdint.h>

#define ALPHA 0.2f
#define NEG_BIG -9000000000000000.0f
#define L2E 1.4426950408889634f

typedef __attribute__((ext_vector_type(8))) short bf16x8;
typedef __attribute__((ext_vector_type(8))) unsigned short u16x8;
typedef __attribute__((ext_vector_type(4))) float f32x4;

__device__ __forceinline__ unsigned short f2bf(float f) {
    unsigned int u = __float_as_uint(f);
    u += 0x7fffu + ((u >> 16) & 1u);   // RNE
    return (unsigned short)(u >> 16);
}

__device__ __forceinline__ void gload_lds16(const void* g, void* l) {
    __builtin_amdgcn_global_load_lds(
        (const __attribute__((address_space(1))) unsigned int*)g,
        (__attribute__((address_space(3))) unsigned int*)l, 16, 0, 0);
}

// ---------------------------------------------------------------------------
// Blocks 0..255: Wtbf[o*256+t] = bf16(W[t*256+o]).
// Block 256:     wa[k] = W[k,:]·a_l ; wa[256+k] = W[k,:]·a_r  (fp32).
// ---------------------------------------------------------------------------
__global__ void wt_wa_kernel(const float* __restrict__ W,
                             const float* __restrict__ a,
                             unsigned short* __restrict__ Wtbf,
                             float* __restrict__ wa) {
    const int t = threadIdx.x;
    if (blockIdx.x < 256) {
        const int o = blockIdx.x;
        Wtbf[o * 256 + t] = f2bf(W[t * 256 + o]);
    } else {
        float sl = 0.f, sr = 0.f;
        const float* wr = W + t * 256;
        for (int o = 0; o < 256; ++o) {
            const float wv = wr[o];
            sl += wv * a[o];
            sr += wv * a[256 + o];
        }
        wa[t] = sl;
        wa[256 + t] = sr;
    }
}

// ---------------------------------------------------------------------------
// One wave per row r: el2[r] = (x[r,:]·wa_l)*log2(e), er2 likewise,
// and xbf[r,:] = bf16(x[r,:]).
// ---------------------------------------------------------------------------
__global__ __launch_bounds__(256) void eler2x_kernel(
    const float* __restrict__ x, const float* __restrict__ wa,
    float* __restrict__ el, float* __restrict__ er,
    unsigned short* __restrict__ xbf)
{
    const int w = threadIdx.x >> 6, l = threadIdx.x & 63;
    const int r = blockIdx.x * 4 + w;       // 0..16383
    const float4 xv = *(const float4*)(x + (size_t)r * 256 + l * 4);
    const float4 al = *(const float4*)(wa + l * 4);
    const float4 ar = *(const float4*)(wa + 256 + l * 4);

    ushort4 xb;
    xb.x = f2bf(xv.x); xb.y = f2bf(xv.y); xb.z = f2bf(xv.z); xb.w = f2bf(xv.w);
    *(ushort4*)(xbf + (size_t)r * 256 + l * 4) = xb;

    float sl = xv.x * al.x + xv.y * al.y + xv.z * al.z + xv.w * al.w;
    float sr = xv.x * ar.x + xv.y * ar.y + xv.z * ar.z + xv.w * ar.w;
#pragma unroll
    for (int off = 32; off >= 1; off >>= 1) {
        sl += __shfl_xor(sl, off);
        sr += __shfl_xor(sr, off);
    }
    if (l == 0) { el[r] = sl * L2E; er[r] = sr * L2E; }
}

// ---------------------------------------------------------------------------
// h_T (256 x 16384) = Wtbf (256x256) @ xbf^T.  Flat batched GEMM.
// 64(m) x 128(n) tiles, K-step 64, grid (128,4) = 512 blocks (2/CU).
// 2-phase: double-buffered LDS, counted vmcnt (loads fly across barriers).
// ---------------------------------------------------------------------------
__global__ __launch_bounds__(256) void gemm_h(
    const unsigned short* __restrict__ A,    // Wtbf 256x256
    const unsigned short* __restrict__ Bt,   // xbf 16384x256
    unsigned short* __restrict__ C)          // h_T 256x16384
{
    __shared__ __align__(16) unsigned short As[2 * 64 * 64];    // 16 KB
    __shared__ __align__(16) unsigned short Bs[2 * 128 * 64];   // 32 KB

    const int tid = threadIdx.x;
    const int w = tid >> 6, l = tid & 63;
    const int q = l >> 4, ml = l & 15;
    const int wm = (w >> 1) * 32;
    const int wn = (w & 1) * 64;
    const int m0 = blockIdx.y * 64;
    const int n0 = blockIdx.x * 128;

    f32x4 acc[2][4];
#pragma unroll
    for (int i = 0; i < 2; ++i)
#pragma unroll
        for (int j = 0; j < 4; ++j) {
            f32x4 z = {0.f, 0.f, 0.f, 0.f};
            acc[i][j] = z;
        }

#define GSTAGE(BI, K0) do {                                                   \
    _Pragma("unroll")                                                         \
    for (int c_ = 0; c_ < 2; ++c_) {                                          \
        const int cb_ = c_ * 256 + (w << 6);                                  \
        const int p_ = cb_ + l;                                               \
        const int r_ = p_ >> 3;                                               \
        const int cc_ = (p_ & 7) ^ (r_ & 7);                                  \
        gload_lds16(A + (size_t)(m0 + r_) * 256 + (K0) + cc_ * 8,             \
                    As + (BI) * 4096 + cb_ * 8);                              \
    }                                                                         \
    _Pragma("unroll")                                                         \
    for (int c_ = 0; c_ < 4; ++c_) {                                          \
        const int cb_ = c_ * 256 + (w << 6);                                  \
        const int p_ = cb_ + l;                                               \
        const int r_ = p_ >> 3;                                               \
        const int cc_ = (p_ & 7) ^ (r_ & 7);                                  \
        gload_lds16(Bt + (size_t)(n0 + r_) * 256 + (K0) + cc_ * 8,            \
                    Bs + (BI) * 8192 + cb_ * 8);                              \
    } } while (0)

    GSTAGE(0, 0);

    for (int s = 0; s < 4; ++s) {
        const int cur = s & 1;
        if (s + 1 < 4) {
            GSTAGE((s + 1) & 1, (s + 1) * 64);
            asm volatile("s_waitcnt vmcnt(6) lgkmcnt(0)" ::: "memory");
        } else {
            asm volatile("s_waitcnt vmcnt(0) lgkmcnt(0)" ::: "memory");
        }
        __builtin_amdgcn_s_barrier();
        __builtin_amdgcn_sched_barrier(0);

        const unsigned short* Ab = As + cur * 4096;
        const unsigned short* Bb = Bs + cur * 8192;
        bf16x8 aF[2][2], bF[2][4];
#pragma unroll
        for (int ks = 0; ks < 2; ++ks) {
#pragma unroll
            for (int mt = 0; mt < 2; ++mt) {
                const int mm = wm + mt * 16 + ml;
                aF[ks][mt] = *(const bf16x8*)(Ab + (mm * 8 + ((ks * 4 + q) ^ (mm & 7))) * 8);
            }
#pragma unroll
            for (int nt = 0; nt < 4; ++nt) {
                const int nn = wn + nt * 16 + ml;
                bF[ks][nt] = *(const bf16x8*)(Bb + (nn * 8 + ((ks * 4 + q) ^ (nn & 7))) * 8);
            }
        }
#pragma unroll
        for (int ks = 0; ks < 2; ++ks)
            for (int mt = 0; mt < 2; ++mt)
                for (int nt = 0; nt < 4; ++nt)
                    acc[mt][nt] = __builtin_amdgcn_mfma_f32_16x16x32_bf16(
                        aF[ks][mt], bF[ks][nt], acc[mt][nt], 0, 0, 0);

        asm volatile("s_waitcnt lgkmcnt(0)" ::: "memory");
        __builtin_amdgcn_s_barrier();
    }
#undef GSTAGE

    for (int mt = 0; mt < 2; ++mt)
        for (int nt = 0; nt < 4; ++nt) {
            const int gn = n0 + wn + nt * 16 + ml;
            for (int r = 0; r < 4; ++r) {
                const int gm = m0 + wm + mt * 16 + q * 4 + r;
                C[(size_t)gm * 16384 + gn] = f2bf(acc[mt][nt][r]);
            }
        }
}

// ---------------------------------------------------------------------------
// Mask pre-pass, log2 domain. One wave per row.
// c2[row] = m2 + log2(sum 2^(e2-m2));  adjacency packed to pk16.
// ---------------------------------------------------------------------------
__global__ __launch_bounds__(256) void mask_kernel(
    const int* __restrict__ adj,
    const float* __restrict__ el,     // log2-scaled
    const float* __restrict__ er,     // log2-scaled
    float* __restrict__ c,            // log2-domain logsumexp
    unsigned short* __restrict__ pk16)
{
    __shared__ unsigned char nibs[4][256];

    const int w = threadIdx.x >> 6, l = threadIdx.x & 63;
    const int row = blockIdx.x * 4 + w;       // 0..16383
    const int b = row >> 10;
    const int* arow = adj + (size_t)row * 1024;
    const float* erb = er + (b << 10);
    const float eli = el[row];

    float ev[16];
    float m = -3.0e38f;
#pragma unroll
    for (int it = 0; it < 4; ++it) {
        const int j = it * 256 + l * 4;
        const int4 av = *(const int4*)(arow + j);
        const float4 erv = *(const float4*)(erb + j);
        float e0 = eli + erv.x; e0 = e0 > 0.f ? e0 : ALPHA * e0; e0 = av.x > 0 ? e0 : NEG_BIG;
        float e1 = eli + erv.y; e1 = e1 > 0.f ? e1 : ALPHA * e1; e1 = av.y > 0 ? e1 : NEG_BIG;
        float e2 = eli + erv.z; e2 = e2 > 0.f ? e2 : ALPHA * e2; e2 = av.z > 0 ? e2 : NEG_BIG;
        float e3 = eli + erv.w; e3 = e3 > 0.f ? e3 : ALPHA * e3; e3 = av.w > 0 ? e3 : NEG_BIG;
        ev[it * 4 + 0] = e0; ev[it * 4 + 1] = e1;
        ev[it * 4 + 2] = e2; ev[it * 4 + 3] = e3;
        m = fmaxf(m, fmaxf(fmaxf(e0, e1), fmaxf(e2, e3)));
        nibs[w][it * 64 + l] =
            (unsigned char)((av.x > 0) | ((av.y > 0) << 1) |
                            ((av.z > 0) << 2) | ((av.w > 0) << 3));
    }
#pragma unroll
    for (int off = 32; off >= 1; off >>= 1) m = fmaxf(m, __shfl_xor(m, off));
    float s = 0.f;
#pragma unroll
    for (int u = 0; u < 16; ++u) s += exp2f(ev[u] - m);
#pragma unroll
    for (int off = 32; off >= 1; off >>= 1) s += __shfl_xor(s, off);
    if (l == 0) c[row] = m + log2f(s);

    const unsigned nr = *(const unsigned int*)(&nibs[w][l * 4]);
    const unsigned short mask16 =
        (unsigned short)((nr & 0xFu) | ((nr >> 4) & 0xF0u) |
                         ((nr >> 8) & 0xF00u) | ((nr >> 12) & 0xF000u));
    pk16[(size_t)row * 64 + l] = mask16;
}

// ---------------------------------------------------------------------------
// PV: out[b, i0..i0+63, :] = P @ h[b].
// Grid 256 (1/CU), 512 threads (8 waves: 2m x 4n).  j-step 32, 32 iters.
// 2-phase: Hs (256 o-rows x 32 j, 16 KB) double-buffered via global_load_lds;
// stage t+1 issued BEFORE computing t; s_waitcnt vmcnt(2) (counted, never 0
// mid-loop) + raw s_barrier -> next tile's loads stay in flight.
// Hs swizzle for 4 chunks/row: slot = cc ^ ((row>>1)&3); read-side bank
// starts = 16*(row&1) + 4*slot -> 8 distinct groups, 2-way (free).
// Ps (64x32, stride 40) double-buffered; P built from el/er/c in log2 domain.
// XCD decode: b = ((bid&7)<<1) | (slot>>4) pins 2 batches (1 MB) per XCD L2;
// each block reads h[b] exactly once (512 KB) -> h_T re-read 134 MB total.
// ---------------------------------------------------------------------------
__global__ __launch_bounds__(512) void pv_kernel(
    const unsigned short* __restrict__ pk16,
    const float* __restrict__ el2,
    const float* __restrict__ er2,
    const float* __restrict__ c2,
    const unsigned short* __restrict__ hT,   // 256 x 16384 (row stride 16384)
    float* __restrict__ out)
{
    __shared__ float er_s[1024];                                  //  4 KB
    __shared__ __align__(16) unsigned short pk_s[64 * 64];        //  8 KB
    __shared__ __align__(16) unsigned short Hs[2 * 256 * 32];     // 32 KB
    __shared__ __align__(16) unsigned short Ps[2 * 64 * 40];      // 10 KB

    const int tid = threadIdx.x;
    const int w = tid >> 6, l = tid & 63;
    const int q = l >> 4, ml = l & 15;
    const int wm = (w >> 2) * 32;       // 0 | 32
    const int wn = (w & 3) * 64;        // 0..192

    const int bid = blockIdx.x;
    const int slot = bid >> 3;                        // 0..31
    const int b = ((bid & 7) << 1) | (slot >> 4);     // 2 batches per XCD
    const int i0 = (slot & 15) * 64;

    // ---- init LDS ----
    *(float2*)(er_s + tid * 2) = *(const float2*)(er2 + (b << 10) + tid * 2);
    *(u16x8*)(pk_s + (tid >> 3) * 64 + (tid & 7) * 8) =
        *(const u16x8*)(pk16 + (size_t)((b << 10) + i0 + (tid >> 3)) * 64 + (tid & 7) * 8);

    // P-build mapping: thread -> row ib (0..63), cols js..js+3 of 32-wide tile
    const int ib = tid >> 3;
    const int js = (tid & 7) * 4;
    const int rg = (b << 10) + i0 + ib;
    const float el2i = el2[rg];
    const float c2i = c2[rg];

    f32x4 acc[2][4];
#pragma unroll
    for (int i = 0; i < 2; ++i)
#pragma unroll
        for (int j = 0; j < 4; ++j) {
            f32x4 z = {0.f, 0.f, 0.f, 0.f};
            acc[i][j] = z;
        }

    const unsigned short* hb = hT + (size_t)b * 1024;

// stage 16 KB: 1024 chunks of 16B, 512 threads -> 2 rounds (2 gload/thread)
#define STAGE(BI, T) do {                                                     \
    const int jb_ = (T) * 32;                                                 \
    _Pragma("unroll")                                                         \
    for (int c_ = 0; c_ < 2; ++c_) {                                          \
        const int cb_ = c_ * 512 + (w << 6);                                  \
        const int p_ = cb_ + l;                                               \
        const int r_ = p_ >> 2;                                               \
        const int cc_ = (p_ & 3) ^ ((r_ >> 1) & 3);                           \
        gload_lds16(hb + (size_t)r_ * 16384 + jb_ + cc_ * 8,                  \
                    Hs + (BI) * 8192 + cb_ * 8);                              \
    } } while (0)

#define BUILD(BI, T) do {                                                     \
    const int jb_ = (T) * 32;                                                 \
    const float4 ev_ = *(const float4*)(er_s + jb_ + js);                     \
    const unsigned hw_ = pk_s[ib * 64 + ((jb_ + js) >> 4)];                   \
    const unsigned mv_ = (hw_ >> (js & 12)) & 0xFu;                           \
    float e0_ = el2i + ev_.x; e0_ = fmaxf(e0_, ALPHA * e0_);                  \
    float e1_ = el2i + ev_.y; e1_ = fmaxf(e1_, ALPHA * e1_);                  \
    float e2_ = el2i + ev_.z; e2_ = fmaxf(e2_, ALPHA * e2_);                  \
    float e3_ = el2i + ev_.w; e3_ = fmaxf(e3_, ALPHA * e3_);                  \
    ushort4 pv_;                                                              \
    pv_.x = (mv_ & 1u) ? f2bf(exp2f(e0_ - c2i)) : (unsigned short)0;          \
    pv_.y = (mv_ & 2u) ? f2bf(exp2f(e1_ - c2i)) : (unsigned short)0;          \
    pv_.z = (mv_ & 4u) ? f2bf(exp2f(e2_ - c2i)) : (unsigned short)0;          \
    pv_.w = (mv_ & 8u) ? f2bf(exp2f(e3_ - c2i)) : (unsigned short)0;          \
    *(ushort4*)(Ps + (BI) * 2560 + ib * 40 + js) = pv_;                       \
    } while (0)

#define COMPUTE(BI) do {                                                      \
    bf16x8 aF_[2], bF_[4];                                                    \
    _Pragma("unroll")                                                         \
    for (int mt_ = 0; mt_ < 2; ++mt_)                                         \
        aF_[mt_] = *(const bf16x8*)(Ps + (BI) * 2560 +                        \
                                    (wm + mt_ * 16 + ml) * 40 + q * 8);       \
    _Pragma("unroll")                                                         \
    for (int nt_ = 0; nt_ < 4; ++nt_) {                                       \
        const int oc_ = wn + nt_ * 16 + ml;                                   \
        const int sl_ = q ^ ((oc_ >> 1) & 3);                                 \
        bF_[nt_] = *(const bf16x8*)(Hs + (BI) * 8192 + oc_ * 32 + sl_ * 8);   \
    }                                                                         \
    _Pragma("unroll")                                                         \
    for (int mt_ = 0; mt_ < 2; ++mt_)                                         \
        _Pragma("unroll")                                                     \
        for (int nt_ = 0; nt_ < 4; ++nt_)                                     \
            acc[mt_][nt_] = __builtin_amdgcn_mfma_f32_16x16x32_bf16(          \
                aF_[mt_], bF_[nt_], acc[mt_][nt_], 0, 0, 0);                  \
    } while (0)

    STAGE(0, 0);
    // init-LDS visibility (er_s/pk_s): lgkm-only barrier, staging stays in flight
    asm volatile("s_waitcnt lgkmcnt(0)" ::: "memory");
    __builtin_amdgcn_s_barrier();

    for (int t = 0; t < 32; ++t) {
        const int cur = t & 1;
        if (t + 1 < 32) STAGE((t + 1) & 1, t + 1);
        BUILD(cur, t);
        if (t + 1 < 32)
            asm volatile("s_waitcnt vmcnt(2) lgkmcnt(0)" ::: "memory");
        else
            asm volatile("s_waitcnt vmcnt(0) lgkmcnt(0)" ::: "memory");
        __builtin_amdgcn_s_barrier();
        __builtin_amdgcn_sched_barrier(0);
        COMPUTE(cur);
        asm volatile("s_waitcnt lgkmcnt(0)" ::: "memory");
        __builtin_amdgcn_s_barrier();
    }

#undef STAGE
#undef BUILD
#undef COMPUTE

    // D layout: col=lane&15, row=(lane>>4)*4+reg
    float* ob = out + (size_t)b * 262144;
#pragma unroll
    for (int mt = 0; mt < 2; ++mt)
#pragma unroll
        for (int nt = 0; nt < 4; ++nt) {
            const int gn = wn + nt * 16 + ml;
#pragma unroll
            for (int r = 0; r < 4; ++r) {
                const int gm = i0 + wm + mt * 16 + q * 4 + r;
                ob[(size_t)gm * 256 + gn] = acc[mt][nt][r];
            }
        }
}

// ---------------------------------------------------------------------------
// Workspace (~19.2 MB):
//   Wtbf (bf16) @ 0        : 131072
//   wa   (f32)  @ 131072   : 2048
//   xbf  (bf16) @ 133120   : 8388608   (16384 x 256)
//   h_T  (bf16) @ 8521728  : 8388608   (256 x 16384)
//   el2  (f32)  @ 16910336 : 65536    (log2-scaled)
//   er2  (f32)  @ 16975872 : 65536    (log2-scaled)
//   c2   (f32)  @ 17041408 : 65536    (log2-domain logsumexp)
//   pk16 (u16)  @ 17106944 : 2097152
// ---------------------------------------------------------------------------
extern "C" void kernel_launch(void* const* d_in, const int* in_sizes, int n_in,
                              void* d_out, int out_size, void* d_ws, size_t ws_size,
                              hipStream_t stream) {
    const float* x   = (const float*)d_in[0];   // (16,1024,256) fp32
    const int*   adj = (const int*)d_in[1];     // (16,1024,1024) int32
    const float* W   = (const float*)d_in[2];   // (256,256) fp32
    const float* a   = (const float*)d_in[3];   // (512,1) fp32
    float* out = (float*)d_out;                 // (16,1024,256) fp32

    char* ws = (char*)d_ws;
    unsigned short* Wtbf  = (unsigned short*)(ws);
    float* wa             = (float*)(ws + 131072);
    unsigned short* xbf   = (unsigned short*)(ws + 133120);
    unsigned short* h_T   = (unsigned short*)(ws + 8521728);
    float* el             = (float*)(ws + 16910336);
    float* er             = (float*)(ws + 16975872);
    float* c              = (float*)(ws + 17041408);
    unsigned short* pk16  = (unsigned short*)(ws + 17106944);

    wt_wa_kernel<<<dim3(257), dim3(256), 0, stream>>>(W, a, Wtbf, wa);

    eler2x_kernel<<<dim3(4096), dim3(256), 0, stream>>>(x, wa, el, er, xbf);

    // h_T (256 x 16384) = Wtbf @ xbf^T
    gemm_h<<<dim3(128, 4), dim3(256), 0, stream>>>(Wtbf, xbf, h_T);

    mask_kernel<<<dim3(4096), dim3(256), 0, stream>>>(adj, el, er, c, pk16);

    pv_kernel<<<dim3(256), dim3(512), 0, stream>>>(pk16, el, er, c, h_T, out);
}